// Round 2
// baseline (381.883 us; speedup 1.0000x reference)
//
#include <hip/hip_runtime.h>

// SLAM layer, fused: h = relu(x_aux@W1+b1); S = h@W2+b2; out[t] = x_main[-1,t,0] @ S[:,t,:]
// N,T,M,A,D = 4,1024,128,64,128.
// Kernel 0: W1->W1T bf16, W2->W2T bf16 into d_ws (block-invariant, done once per launch).
// Kernel 1: one block per t; bf16 MFMA 16x16x32, fp32 accum; W frags read from global (L2);
//           LDS only for Xa (phase1 B), h (phase1->2), ST (phase2->3). 70.6 KB -> 2 blocks/CU.

#define TT 1024
#define MM 128
#define AA 64
#define DD 128

typedef float  f32x4  __attribute__((ext_vector_type(4)));
typedef __bf16 bf16x8 __attribute__((ext_vector_type(8)));
typedef __bf16 bf16x4 __attribute__((ext_vector_type(4)));

__global__ __launch_bounds__(512, 1)
void slam_prep(const float* __restrict__ W1, const float* __restrict__ W2,
               __bf16* __restrict__ ws)
{
    int idx = blockIdx.x * 512 + threadIdx.x;            // 48 blocks * 512 = 24576 = 8192 + 16384
    if (idx < DD * AA) {                                  // W1T[d][a] = W1[a][d]
        int d = idx >> 6, a = idx & 63;
        ws[idx] = (__bf16)W1[a * DD + d];
    } else {
        int i2 = idx - DD * AA;                           // W2T[k][d] = W2[d][k]
        int k = i2 >> 7, d = i2 & 127;
        ws[DD * AA + i2] = (__bf16)W2[d * MM + k];
    }
}

__global__ __launch_bounds__(512, 4)
void slam_fused(const float* __restrict__ xm, const float* __restrict__ xa,
                const float* __restrict__ b1, const float* __restrict__ b2,
                const __bf16* __restrict__ wsW1T, const __bf16* __restrict__ wsW2T,
                float* __restrict__ out)
{
    __shared__ __bf16 ldsA[17408];   // phase1: Xa[128][72] (first 9216); phase>=2: ST[128][136]
    __shared__ __bf16 ldsH[17408];   // h[128][136] (row=m, col=d)
    __shared__ float  ldsB1[128];
    __shared__ float  ldsB2[128];

    const int t    = blockIdx.x;
    const int tid  = threadIdx.x;
    const int lane = tid & 63;
    const int wv   = tid >> 6;       // 0..7
    const int n    = lane & 15;
    const int q    = lane >> 4;

    // ---- prefetch phase-3 A operand (main_last[t] rows), convert to bf16 frags now ----
    const float* arow = xm + (size_t)3 * TT * MM * MM + ((size_t)t * MM + wv * 16 + n) * MM;
    bf16x8 a3[4];
#pragma unroll
    for (int ks = 0; ks < 4; ++ks) {
        f32x4 lo = *(const f32x4*)(arow + ks * 32 + q * 8);
        f32x4 hi = *(const f32x4*)(arow + ks * 32 + q * 8 + 4);
        bf16x8 v;
        v[0] = (__bf16)lo[0]; v[1] = (__bf16)lo[1]; v[2] = (__bf16)lo[2]; v[3] = (__bf16)lo[3];
        v[4] = (__bf16)hi[0]; v[5] = (__bf16)hi[1]; v[6] = (__bf16)hi[2]; v[7] = (__bf16)hi[3];
        a3[ks] = v;
    }

    // ---- stage Xa: x_aux[m, t, :] -> ldsA[m][a], stride 72 ----
#pragma unroll
    for (int p = 0; p < 4; ++p) {
        int m = p * 32 + (tid >> 4);
        int c = (tid & 15) * 4;
        f32x4 v = *(const f32x4*)(xa + ((size_t)m * TT + t) * AA + c);
        bf16x4 pk;
        pk[0] = (__bf16)v[0]; pk[1] = (__bf16)v[1]; pk[2] = (__bf16)v[2]; pk[3] = (__bf16)v[3];
        *(bf16x4*)(ldsA + m * 72 + c) = pk;
    }
    if (tid < 128)      ldsB1[tid] = b1[tid];
    else if (tid < 256) ldsB2[tid - 128] = b2[tid - 128];

    __syncthreads();

    f32x4 acc[8];

    // ---- phase 1: D[d][m] = sum_a W1T[d][a] * Xa[m][a]; wave wv owns d-band ----
    {
        const __bf16* w1r = wsW1T + (wv * 16 + n) * AA;
        bf16x8 a1[2];
        a1[0] = *(const bf16x8*)(w1r + q * 8);
        a1[1] = *(const bf16x8*)(w1r + 32 + q * 8);
#pragma unroll
        for (int mt = 0; mt < 8; ++mt) acc[mt] = (f32x4){0.f, 0.f, 0.f, 0.f};
#pragma unroll
        for (int mt = 0; mt < 8; ++mt) {
#pragma unroll
            for (int ks = 0; ks < 2; ++ks) {
                bf16x8 bb = *(const bf16x8*)(ldsA + (mt * 16 + n) * 72 + ks * 32 + q * 8);
                acc[mt] = __builtin_amdgcn_mfma_f32_16x16x32_bf16(a1[ks], bb, acc[mt], 0, 0, 0);
            }
        }
        int dbase = wv * 16 + q * 4;
        float bv0 = ldsB1[dbase + 0], bv1 = ldsB1[dbase + 1];
        float bv2 = ldsB1[dbase + 2], bv3 = ldsB1[dbase + 3];
#pragma unroll
        for (int mt = 0; mt < 8; ++mt) {
            int m = mt * 16 + n;
            bf16x4 pk;
            pk[0] = (__bf16)fmaxf(acc[mt][0] + bv0, 0.f);
            pk[1] = (__bf16)fmaxf(acc[mt][1] + bv1, 0.f);
            pk[2] = (__bf16)fmaxf(acc[mt][2] + bv2, 0.f);
            pk[3] = (__bf16)fmaxf(acc[mt][3] + bv3, 0.f);
            *(bf16x4*)(ldsH + m * 136 + dbase) = pk;
        }
    }
    __syncthreads();

    // ---- phase 2: D[j][k] = sum_d h[j][d] * W2[d][k]; wave wv owns j-band; store ST[k][j] ----
    {
        bf16x8 a2[4];
#pragma unroll
        for (int ks = 0; ks < 4; ++ks)
            a2[ks] = *(const bf16x8*)(ldsH + (wv * 16 + n) * 136 + ks * 32 + q * 8);
#pragma unroll
        for (int kt = 0; kt < 8; ++kt) acc[kt] = (f32x4){0.f, 0.f, 0.f, 0.f};
#pragma unroll
        for (int kt = 0; kt < 8; ++kt) {
            const __bf16* w2r = wsW2T + (kt * 16 + n) * DD + q * 8;
#pragma unroll
            for (int ks = 0; ks < 4; ++ks) {
                bf16x8 bb = *(const bf16x8*)(w2r + ks * 32);
                acc[kt] = __builtin_amdgcn_mfma_f32_16x16x32_bf16(a2[ks], bb, acc[kt], 0, 0, 0);
            }
        }
        int jbase = wv * 16 + q * 4;
#pragma unroll
        for (int kt = 0; kt < 8; ++kt) {
            int k = kt * 16 + n;
            float bv = ldsB2[k];
            bf16x4 pk;
            pk[0] = (__bf16)(acc[kt][0] + bv);
            pk[1] = (__bf16)(acc[kt][1] + bv);
            pk[2] = (__bf16)(acc[kt][2] + bv);
            pk[3] = (__bf16)(acc[kt][3] + bv);
            *(bf16x4*)(ldsA + k * 136 + jbase) = pk;   // ldsA: Xa dead after phase-1 barrier
        }
    }
    __syncthreads();

    // ---- phase 3: out[i][k] = sum_j A[i][j] * S[j][k]; wave wv owns i-band ----
    {
#pragma unroll
        for (int kt = 0; kt < 8; ++kt) acc[kt] = (f32x4){0.f, 0.f, 0.f, 0.f};
#pragma unroll
        for (int kt = 0; kt < 8; ++kt) {
#pragma unroll
            for (int ks = 0; ks < 4; ++ks) {
                bf16x8 bb = *(const bf16x8*)(ldsA + (kt * 16 + n) * 136 + ks * 32 + q * 8);
                acc[kt] = __builtin_amdgcn_mfma_f32_16x16x32_bf16(a3[ks], bb, acc[kt], 0, 0, 0);
            }
        }
        float* orow = out + (size_t)t * MM * MM;
        int ibase = wv * 16 + q * 4;
#pragma unroll
        for (int kt = 0; kt < 8; ++kt) {
            int k = kt * 16 + n;
#pragma unroll
            for (int r = 0; r < 4; ++r)
                orow[(size_t)(ibase + r) * MM + k] = acc[kt][r];
        }
    }
}

extern "C" void kernel_launch(void* const* d_in, const int* in_sizes, int n_in,
                              void* d_out, int out_size, void* d_ws, size_t ws_size,
                              hipStream_t stream) {
    const float* xm = (const float*)d_in[0];
    const float* xa = (const float*)d_in[1];
    const float* W1 = (const float*)d_in[2];
    const float* b1 = (const float*)d_in[3];
    const float* W2 = (const float*)d_in[4];
    const float* b2 = (const float*)d_in[5];
    float* out = (float*)d_out;

    __bf16* wsW1T = (__bf16*)d_ws;              // [128][64]
    __bf16* wsW2T = wsW1T + DD * AA;            // [128][128]

    slam_prep<<<dim3(48), dim3(512), 0, stream>>>(W1, W2, wsW1T);
    slam_fused<<<dim3(TT), dim3(512), 0, stream>>>(xm, xa, b1, b2, wsW1T, wsW2T, out);
}